// Round 6
// baseline (57.884 us; speedup 1.0000x reference)
//
#include <hip/hip_runtime.h>
#include <math.h>

// ---------------------------------------------------------------------------
// ZBL repulsion, R6: minimize cache-line lookups per wave.
//  - disp staged via coalesced float4 -> LDS (12 lines/wave, not 36)
//  - gather uint8 Z (100 KB table, ~33% L1 hit) instead of float2 (800 KB);
//    z -> za via 4-copy padded LDS table (ds_read_b32, ~2-way = free)
//  - cp = Z_i*Z_j exact integer multiply in registers
//  - wave-uniform fast path: 6 shfl_xor butterfly when whole wave same key
//  - native exp2/rcp/rsq lean math (5 exp2 per pair)
// ---------------------------------------------------------------------------

#define LOG2E 1.4426950408889634f
#define TSTR 257                  // table copy stride (floats); 4 copies

static __device__ __forceinline__ float rcpf_(float x)  { return __builtin_amdgcn_rcpf(x); }
static __device__ __forceinline__ float rsqf_(float x)  { return __builtin_amdgcn_rsqf(x); }
static __device__ __forceinline__ float exp2f_(float x) { return __builtin_amdgcn_exp2f(x); }
static __device__ __forceinline__ float log2f_(float x) { return __builtin_amdgcn_logf(x); }

__global__ void zbl_build_z8(const float* __restrict__ an,
                             unsigned char* __restrict__ z8, int n) {
    int i = blockIdx.x * blockDim.x + threadIdx.x;
    if (i >= n) return;
    int z = (int)(an[i] + 0.5f);
    z8[i] = (unsigned char)min(max(z, 1), 255);
}

__global__ __launch_bounds__(256) void zbl_pair_kernel(
    const float* __restrict__ disp,        // [P*3]
    const int*   __restrict__ idx_i,       // sorted
    const int*   __restrict__ idx_j,
    const float* __restrict__ batch_mask,  // [P]
    const unsigned char* __restrict__ z8,  // [N] atomic number as u8
    const float* __restrict__ a_coef_ptr,  // 1
    const float* __restrict__ a_exp_ptr,   // 1
    const float* __restrict__ phi_c,       // 4
    const float* __restrict__ phi_e,       // 4
    float* __restrict__ out_acc,           // [N] accumulator (pre-zeroed)
    int nP)
{
    __shared__ float sdisp[256 * 3];       // 3 KB
    __shared__ float za_t[4 * TSTR];       // 4 padded copies of za(z) table

    const int tid  = threadIdx.x;
    const int base = blockIdx.x * 256;

    // ---- build za table: za(z) = z^|a_exp| = 2^(ae*log2(z))
    {
        const float ae = fabsf(a_exp_ptr[0]);
        for (int idx = tid; idx < 4 * TSTR; idx += 256) {
            int z = idx % TSTR;
            za_t[idx] = exp2f_(ae * log2f_((float)max(z, 1)));
        }
    }

    // ---- stage 256 pairs' displacements (768 floats = 192 float4), coalesced
    {
        long gbase = (long)base * 3;
        long total = (long)nP * 3;
        if (tid < 192) {
            long g = gbase + (long)tid * 4;
            if (g + 3 < total) {
                float4 v = *reinterpret_cast<const float4*>(disp + g);
                reinterpret_cast<float4*>(sdisp)[tid] = v;
            } else {
                #pragma unroll
                for (int k = 0; k < 4; ++k)
                    sdisp[tid * 4 + k] = (g + k < total) ? disp[g + k] : 0.0f;
            }
        }
    }
    __syncthreads();

    const int p = base + tid;
    float rep = 0.0f;
    int   key = -1;

    if (p < nP) {
        const int ii = idx_i[p];
        const int jj = idx_j[p];
        const int zi = (int)z8[ii];
        const int zj = (int)z8[jj];
        const float bm = batch_mask[p];

        const float add = 1.0f - bm;
        const float dx = sdisp[tid * 3 + 0] + add;
        const float dy = sdisp[tid * 3 + 1] + add;
        const float dz = sdisp[tid * 3 + 2] + add;

        // per-thread uniforms (compiler hoists/scalarizes)
        const float ac_inv = rcpf_(fmaxf(fabsf(a_coef_ptr[0]), 1e-10f));
        float c0 = fabsf(phi_c[0]), c1 = fabsf(phi_c[1]);
        float c2 = fabsf(phi_c[2]), c3 = fabsf(phi_c[3]);
        const float cinv = rcpf_(fmaxf(c0 + c1 + c2 + c3, 1e-10f));
        c0 *= cinv; c1 *= cinv; c2 *= cinv; c3 *= cinv;
        const float e0 = fmaxf(fabsf(phi_e[0]), 1e-10f);
        const float e1 = fmaxf(fabsf(phi_e[1]), 1e-10f);
        const float e2 = fmaxf(fabsf(phi_e[2]), 1e-10f);
        const float e3 = fmaxf(fabsf(phi_e[3]), 1e-10f);

        // za from LDS table (copy per 16-lane group to spread banks)
        const int cbase = ((tid >> 4) & 3) * TSTR;
        const float za_i = za_t[cbase + zi];
        const float za_j = za_t[cbase + zj];

        float d2   = fmaxf(dx * dx + dy * dy + dz * dz, 1e-20f);
        float rsq  = rsqf_(d2);
        float dist = d2 * rsq;                 // sqrt(d2); 1/dist == rsq

        // smooth_switch(dist,0,10) = 1/(1+exp(1/tc - 1/(1-tc)))
        float tt = dist * 0.1f;
        float tc = fminf(fmaxf(tt, 1e-9f), 1.0f - 1e-9f);
        float u  = (1.0f - 2.0f * tc) * rcpf_(tc - tc * tc);
        float s  = rcpf_(1.0f + exp2f_(u * LOG2E));
        float sw = (tt >= 1.0f) ? 1.0f : s;    // tt>0 always since dist>=1e-10

        float za_sum = za_i + za_j;
        float arg  = fminf(dist * za_sum * ac_inv, 1e6f);
        float narg = -arg * LOG2E;
        float phi  = c0 * exp2f_(e0 * narg) + c1 * exp2f_(e1 * narg) +
                     c2 * exp2f_(e2 * narg) + c3 * exp2f_(e3 * narg);
        phi = fminf(fmaxf(phi, 1e-30f), 1e6f);

        float cp   = fminf((float)(zi * zj), 1e4f);   // exact integer product
        float brep = fminf(0.5f * cp * rsq, 1e6f);
        float r    = brep * phi * fmaxf(sw, 1e-30f);
        r = fminf(fmaxf(r, 0.0f), 1e6f);
        if (!(r == r)) r = 0.0f;
        rep = r * bm;
        key = ii;
    }

    // ---- reduction on sorted keys
    const int lane = tid & 63;
    const int k0 = __shfl(key, 0);
    if (__all(key == k0)) {
        // whole wave same key (common: avg run length == wave size)
        float v = rep;
        #pragma unroll
        for (int d = 1; d < 64; d <<= 1) v += __shfl_xor(v, d);
        if (lane == 0 && k0 >= 0) atomicAdd(&out_acc[k0], v);
    } else {
        // segmented suffix-scan
        float v = rep;
        int   k = key;
        #pragma unroll
        for (int d = 1; d < 64; d <<= 1) {
            float nv = __shfl_down(v, d);
            int   nk = __shfl_down(k, d);
            if (lane + d < 64 && nk == k) v += nv;
        }
        int pk = __shfl_up(k, 1);
        bool head = (lane == 0) || (pk != k);
        if (head && k >= 0) atomicAdd(&out_acc[k], v);
    }
}

__global__ void zbl_epilogue(float* __restrict__ out,
                             const float* __restrict__ atom_mask, int n) {
    int i = blockIdx.x * blockDim.x + threadIdx.x;
    if (i >= n) return;
    float v = out[i] * atom_mask[i];
    v = fminf(fmaxf(v, 0.0f), 1e6f);
    if (!(v == v)) v = 0.0f;
    out[i] = v * 0.01f;
}

extern "C" void kernel_launch(void* const* d_in, const int* in_sizes, int n_in,
                              void* d_out, int out_size, void* d_ws, size_t ws_size,
                              hipStream_t stream) {
    const float* an         = (const float*)d_in[0];
    const float* disp       = (const float*)d_in[1];
    const int*   idx_i      = (const int*)d_in[2];
    const int*   idx_j      = (const int*)d_in[3];
    const float* atom_mask  = (const float*)d_in[4];
    const float* batch_mask = (const float*)d_in[5];
    // d_in[6] batch_segments, d_in[7] batch_size: unused by the reference math
    const float* a_coef     = (const float*)d_in[8];
    const float* a_exp      = (const float*)d_in[9];
    const float* phi_c      = (const float*)d_in[10];
    const float* phi_e      = (const float*)d_in[11];

    const int nA = in_sizes[0];
    const int nP = in_sizes[2];
    float* out = (float*)d_out;

    hipMemsetAsync(d_out, 0, (size_t)out_size * sizeof(float), stream);

    unsigned char* z8 = (unsigned char*)d_ws;   // 100 KB, ws is ample

    zbl_build_z8<<<(nA + 255) / 256, 256, 0, stream>>>(an, z8, nA);
    zbl_pair_kernel<<<(nP + 255) / 256, 256, 0, stream>>>(
        disp, idx_i, idx_j, batch_mask, z8, a_coef, a_exp, phi_c, phi_e, out, nP);
    zbl_epilogue<<<(nA + 255) / 256, 256, 0, stream>>>(out, atom_mask, nA);
}